// Round 1
// baseline (2916.975 us; speedup 1.0000x reference)
//
#include <hip/hip_runtime.h>

#define NN 100000
#define EE 3200000
#define HH 75

// ---------------- CSR build ----------------

__global__ __launch_bounds__(256) void hist_kernel(const int* __restrict__ dst,
                                                   int* __restrict__ counts) {
  int e = blockIdx.x * 256 + threadIdx.x;
  if (e < EE) atomicAdd(&counts[dst[e]], 1);
}

__global__ __launch_bounds__(1024) void scan_kernel(const int* __restrict__ counts,
                                                    int* __restrict__ row_start,
                                                    int* __restrict__ cursor) {
  __shared__ int sbuf[1024];
  int tid = threadIdx.x;
  int running = 0;
  for (int base = 0; base < NN; base += 1024) {
    int idx = base + tid;
    int c = (idx < NN) ? counts[idx] : 0;
    int v = c;
    sbuf[tid] = v;
    __syncthreads();
    for (int off = 1; off < 1024; off <<= 1) {
      int t = (tid >= off) ? sbuf[tid - off] : 0;
      __syncthreads();
      v += t;
      sbuf[tid] = v;
      __syncthreads();
    }
    if (idx < NN) {
      int ex = running + v - c;
      row_start[idx] = ex;
      cursor[idx] = ex;
    }
    running += sbuf[1023];
    __syncthreads();
  }
  if (tid == 0) row_start[NN] = running;
}

__global__ __launch_bounds__(256) void fill_kernel(const int* __restrict__ src,
                                                   const int* __restrict__ dst,
                                                   int* __restrict__ cursor,
                                                   int* __restrict__ csr) {
  int e = blockIdx.x * 256 + threadIdx.x;
  if (e < EE) {
    int p = atomicAdd(&cursor[dst[e]], 1);
    csr[p] = src[e];
  }
}

// ---------------- aggregation + eps: z = (1+eps)*xt + sum_{in-edges} xt[src] ----------------

__global__ __launch_bounds__(256) void aggz_kernel(const float* __restrict__ xt, int xs,
                                                   const int* __restrict__ rs,
                                                   const int* __restrict__ csr,
                                                   const float* __restrict__ eps,
                                                   float* __restrict__ z) {
  int tid = threadIdx.x;
  if (tid >= 225) return;
  int local = tid / 75;
  int f = tid - local * 75;
  int n = blockIdx.x * 3 + local;
  if (n >= NN) return;
  int e0 = rs[n], e1 = rs[n + 1];
  float s = 0.f;
  for (int e = e0; e < e1; ++e) {
    int src = csr[e];
    s += xt[src * xs + f];
  }
  float ep = 1.0f + eps[0];
  z[n * 75 + f] = ep * xt[n * xs + f] + s;
}

// ---------------- shared GEMM helpers ----------------

// stage 64 rows (stride is) into tile[64*75]
__device__ __forceinline__ void stage_tile(const float* __restrict__ in, int is, int row0,
                                           float* tile, int tid) {
  for (int i = tid; i < 64 * 75; i += 256) {
    int r = i / 75, c = i - r * 75;
    int gr = row0 + r;
    tile[i] = (gr < NN) ? in[gr * is + c] : 0.f;
  }
}

// stage transposed 75x75 block of W (rows [off, off+75), each row 75 wide) as wsx[k*75+f] = W[(off+f)*75+k]
__device__ __forceinline__ void stagew_t(const float* __restrict__ W, int off, float* wsx,
                                         int tid) {
  for (int i = tid; i < 5625; i += 256) {
    int fr = i / 75;
    int kk = i - fr * 75;
    wsx[kk * 75 + fr] = W[(off + fr) * 75 + kk];
  }
}

// acc[4][5] += tile_rows . W   (W k-major: wsx[k*75+f])
__device__ __forceinline__ void kloop75(const float* tile, const float* wsx, int ty, int tx,
                                        float acc[4][5]) {
  for (int k = 0; k < 75; ++k) {
    float a[4], w[5];
#pragma unroll
    for (int i = 0; i < 4; ++i) a[i] = tile[(ty + 16 * i) * 75 + k];
#pragma unroll
    for (int j = 0; j < 5; ++j) w[j] = wsx[k * 75 + tx + 16 * j];
#pragma unroll
    for (int i = 0; i < 4; ++i)
#pragma unroll
      for (int j = 0; j < 5; ++j) acc[i][j] += a[i] * w[j];
  }
}

// ---------------- GIN MLP: m = relu(relu(z@w1+b1)@w2+b2) ----------------

__global__ __launch_bounds__(256) void mlp_kernel(const float* __restrict__ z,
                                                  const float* __restrict__ w1,
                                                  const float* __restrict__ b1,
                                                  const float* __restrict__ w2,
                                                  const float* __restrict__ b2,
                                                  float* __restrict__ mout) {
  __shared__ float wa[5632];
  __shared__ float wb[5632];
  __shared__ float bia[80];
  __shared__ float bib[80];
  __shared__ float tile[64 * 75];
  int tid = threadIdx.x;
  int row0 = blockIdx.x * 64;
  for (int i = tid; i < 5625; i += 256) {
    wa[i] = w1[i];
    wb[i] = w2[i];
  }
  if (tid < 80) {
    bia[tid] = (tid < 75) ? b1[tid] : 0.f;
    bib[tid] = (tid < 75) ? b2[tid] : 0.f;
  }
  stage_tile(z, 75, row0, tile, tid);
  __syncthreads();
  int ty = tid >> 4, tx = tid & 15;
  float acc[4][5];
#pragma unroll
  for (int i = 0; i < 4; ++i)
#pragma unroll
    for (int j = 0; j < 5; ++j) acc[i][j] = bia[tx + 16 * j];
  kloop75(tile, wa, ty, tx, acc);
  __syncthreads();
#pragma unroll
  for (int i = 0; i < 4; ++i)
#pragma unroll
    for (int j = 0; j < 5; ++j) {
      int f = tx + 16 * j;
      if (f < 75) tile[(ty + 16 * i) * 75 + f] = fmaxf(acc[i][j], 0.f);
    }
  __syncthreads();
  float acc2[4][5];
#pragma unroll
  for (int i = 0; i < 4; ++i)
#pragma unroll
    for (int j = 0; j < 5; ++j) acc2[i][j] = bib[tx + 16 * j];
  kloop75(tile, wb, ty, tx, acc2);
#pragma unroll
  for (int i = 0; i < 4; ++i)
#pragma unroll
    for (int j = 0; j < 5; ++j) {
      int f = tx + 16 * j;
      int gr = row0 + ty + 16 * i;
      if (f < 75 && gr < NN) mout[gr * 75 + f] = fmaxf(acc2[i][j], 0.f);
    }
}

// ---------------- GRU step ----------------

__global__ __launch_bounds__(256) void gru_kernel(const float* __restrict__ m,
                                                  const float* __restrict__ h, int hs,
                                                  const float* __restrict__ w_ih,
                                                  const float* __restrict__ w_hh,
                                                  const float* __restrict__ b_ih,
                                                  const float* __restrict__ b_hh,
                                                  float* __restrict__ hout,
                                                  float* __restrict__ hout2) {
  __shared__ float mt[64 * 75];
  __shared__ float ht[64 * 75];
  __shared__ float wsx[5632];
  __shared__ float bih[240];
  __shared__ float bhh[240];
  int tid = threadIdx.x;
  int row0 = blockIdx.x * 64;
  if (tid < 240) {
    bih[tid] = (tid < 225) ? b_ih[tid] : 0.f;
    bhh[tid] = (tid < 225) ? b_hh[tid] : 0.f;
  }
  stage_tile(m, 75, row0, mt, tid);
  stage_tile(h, hs, row0, ht, tid);
  stagew_t(w_ih, 0, wsx, tid);
  __syncthreads();
  int ty = tid >> 4, tx = tid & 15;
  float gr_[4][5], gz_[4][5], an_[4][5], hn_[4][5];
#pragma unroll
  for (int i = 0; i < 4; ++i)
#pragma unroll
    for (int j = 0; j < 5; ++j) {
      int f = tx + 16 * j;
      gr_[i][j] = bih[f] + bhh[f];
      gz_[i][j] = bih[75 + f] + bhh[75 + f];
      an_[i][j] = bih[150 + f];
      hn_[i][j] = bhh[150 + f];
    }
  // r gate
  kloop75(mt, wsx, ty, tx, gr_);
  __syncthreads();
  stagew_t(w_hh, 0, wsx, tid);
  __syncthreads();
  kloop75(ht, wsx, ty, tx, gr_);
#pragma unroll
  for (int i = 0; i < 4; ++i)
#pragma unroll
    for (int j = 0; j < 5; ++j) gr_[i][j] = 1.f / (1.f + expf(-gr_[i][j]));
  // z gate
  __syncthreads();
  stagew_t(w_ih, 75, wsx, tid);
  __syncthreads();
  kloop75(mt, wsx, ty, tx, gz_);
  __syncthreads();
  stagew_t(w_hh, 75, wsx, tid);
  __syncthreads();
  kloop75(ht, wsx, ty, tx, gz_);
#pragma unroll
  for (int i = 0; i < 4; ++i)
#pragma unroll
    for (int j = 0; j < 5; ++j) gz_[i][j] = 1.f / (1.f + expf(-gz_[i][j]));
  // n gate (two separate accumulators: n = tanh(inn + r*hn))
  __syncthreads();
  stagew_t(w_ih, 150, wsx, tid);
  __syncthreads();
  kloop75(mt, wsx, ty, tx, an_);
  __syncthreads();
  stagew_t(w_hh, 150, wsx, tid);
  __syncthreads();
  kloop75(ht, wsx, ty, tx, hn_);
  // combine + store
#pragma unroll
  for (int i = 0; i < 4; ++i)
#pragma unroll
    for (int j = 0; j < 5; ++j) {
      int f = tx + 16 * j;
      int r = ty + 16 * i;
      int gn = row0 + r;
      if (f < 75 && gn < NN) {
        float nv = tanhf(an_[i][j] + gr_[i][j] * hn_[i][j]);
        float hv = ht[r * 75 + f];
        float o = (1.f - gz_[i][j]) * nv + gz_[i][j] * hv;
        hout[gn * 225 + f] = o;
        if (hout2) hout2[gn * 75 + f] = o;
      }
    }
}

// ---------------- readout ----------------

// r1 = relu(cat @ wc1 + bc1), cat: N x 225 (stride 225), wc1: 225 x 150
__global__ __launch_bounds__(256) void read1_kernel(const float* __restrict__ cat,
                                                    const float* __restrict__ wc1,
                                                    const float* __restrict__ bc1,
                                                    float* __restrict__ r1) {
  __shared__ float wsx[11264];
  __shared__ float tile[64 * 75];
  __shared__ float bias[160];
  int tid = threadIdx.x;
  int row0 = blockIdx.x * 64;
  if (tid < 160) bias[tid] = (tid < 150) ? bc1[tid] : 0.f;
  int ty = tid >> 4, tx = tid & 15;
  float acc[4][10];
  __syncthreads();
#pragma unroll
  for (int i = 0; i < 4; ++i)
#pragma unroll
    for (int j = 0; j < 10; ++j) acc[i][j] = bias[tx + 16 * j];
  for (int kc = 0; kc < 3; ++kc) {
    __syncthreads();
    for (int i = tid; i < 11250; i += 256) wsx[i] = wc1[kc * 11250 + i];
    stage_tile(cat + kc * 75, 225, row0, tile, tid);
    __syncthreads();
    for (int k = 0; k < 75; ++k) {
      float a[4], w[10];
#pragma unroll
      for (int i = 0; i < 4; ++i) a[i] = tile[(ty + 16 * i) * 75 + k];
#pragma unroll
      for (int j = 0; j < 10; ++j) w[j] = wsx[k * 150 + tx + 16 * j];
#pragma unroll
      for (int i = 0; i < 4; ++i)
#pragma unroll
        for (int j = 0; j < 10; ++j) acc[i][j] += a[i] * w[j];
    }
  }
#pragma unroll
  for (int i = 0; i < 4; ++i)
#pragma unroll
    for (int j = 0; j < 10; ++j) {
      int f = tx + 16 * j;
      int gr = row0 + ty + 16 * i;
      if (f < 150 && gr < NN) r1[gr * 150 + f] = fmaxf(acc[i][j], 0.f);
    }
}

// out = r1 @ wc2 + bc2, r1: N x 150, wc2: 150 x 75
__global__ __launch_bounds__(256) void read2_kernel(const float* __restrict__ r1,
                                                    const float* __restrict__ wc2,
                                                    const float* __restrict__ bc2,
                                                    float* __restrict__ out) {
  __shared__ float wsx[5632];
  __shared__ float tile[64 * 75];
  __shared__ float bias[80];
  int tid = threadIdx.x;
  int row0 = blockIdx.x * 64;
  if (tid < 80) bias[tid] = (tid < 75) ? bc2[tid] : 0.f;
  int ty = tid >> 4, tx = tid & 15;
  float acc[4][5];
  __syncthreads();
#pragma unroll
  for (int i = 0; i < 4; ++i)
#pragma unroll
    for (int j = 0; j < 5; ++j) acc[i][j] = bias[tx + 16 * j];
  for (int kc = 0; kc < 2; ++kc) {
    __syncthreads();
    for (int i = tid; i < 5625; i += 256) wsx[i] = wc2[kc * 5625 + i];
    stage_tile(r1 + kc * 75, 150, row0, tile, tid);
    __syncthreads();
    kloop75(tile, wsx, ty, tx, acc);
  }
#pragma unroll
  for (int i = 0; i < 4; ++i)
#pragma unroll
    for (int j = 0; j < 5; ++j) {
      int f = tx + 16 * j;
      int gr = row0 + ty + 16 * i;
      if (f < 75 && gr < NN) out[gr * 75 + f] = acc[i][j];
    }
}

// ---------------- launch ----------------

extern "C" void kernel_launch(void* const* d_in, const int* in_sizes, int n_in,
                              void* d_out, int out_size, void* d_ws, size_t ws_size,
                              hipStream_t stream) {
  const float* x    = (const float*)d_in[0];
  const int*   ei   = (const int*)d_in[1];
  const float* eps  = (const float*)d_in[2];
  const float* w1   = (const float*)d_in[3];
  const float* b1   = (const float*)d_in[4];
  const float* w2   = (const float*)d_in[5];
  const float* b2   = (const float*)d_in[6];
  const float* w_ih = (const float*)d_in[7];
  const float* w_hh = (const float*)d_in[8];
  const float* b_ih = (const float*)d_in[9];
  const float* b_hh = (const float*)d_in[10];
  const float* wc1  = (const float*)d_in[11];
  const float* bc1  = (const float*)d_in[12];
  const float* wc2  = (const float*)d_in[13];
  const float* bc2  = (const float*)d_in[14];

  const int* srcv = ei;
  const int* dstv = ei + EE;

  float* out_x = (float*)d_out;            // N*75 (final node states)
  float* out_r = out_x + NN * HH;          // N*75 (readout)

  float* wsf  = (float*)d_ws;
  float* zb   = wsf;                       // 7.5M floats
  float* mb   = wsf + 7500000;             // 7.5M floats
  float* catb = wsf + 15000000;            // 22.5M floats
  float* r1b  = wsf;                       // reuse z+m region (15M floats)
  int*   csr  = (int*)(wsf + 37500000);    // E ints
  int*   rs   = csr + EE;                  // N+1 ints
  int*   curp = rs + (NN + 1);             // N ints
  int*   cnts = curp + NN;                 // N ints

  hipMemsetAsync(cnts, 0, NN * sizeof(int), stream);
  hist_kernel<<<(EE + 255) / 256, 256, 0, stream>>>(dstv, cnts);
  scan_kernel<<<1, 1024, 0, stream>>>(cnts, rs, curp);
  fill_kernel<<<(EE + 255) / 256, 256, 0, stream>>>(srcv, dstv, curp, csr);

  int gb = (NN + 63) / 64;   // 1563
  int ab = (NN + 2) / 3;     // 33334

  const float* xt = x;
  int xs = 75;
  for (int it = 0; it < 3; ++it) {
    aggz_kernel<<<ab, 256, 0, stream>>>(xt, xs, rs, csr, eps, zb);
    mlp_kernel<<<gb, 256, 0, stream>>>(zb, w1, b1, w2, b2, mb);
    gru_kernel<<<gb, 256, 0, stream>>>(mb, xt, xs, w_ih, w_hh, b_ih, b_hh,
                                       catb + it * 75, (it == 2) ? out_x : nullptr);
    xt = catb + it * 75;
    xs = 225;
  }
  read1_kernel<<<gb, 256, 0, stream>>>(catb, wc1, bc1, r1b);
  read2_kernel<<<gb, 256, 0, stream>>>(r1b, wc2, bc2, out_r);
}

// Round 2
// 2400.015 us; speedup vs baseline: 1.2154x; 1.2154x over previous
//
#include <hip/hip_runtime.h>

#define NN 100000
#define EE 3200000

typedef unsigned short u16;
typedef unsigned int u32;

__device__ __forceinline__ float b2f(u16 h) { return __uint_as_float(((u32)h) << 16); }
__device__ __forceinline__ u16 f2b(float f) {
  u32 u = __float_as_uint(f);
  u32 r = (u + 0x7FFFu + ((u >> 16) & 1u)) >> 16;
  return (u16)r;
}

// ---------------- CSR build ----------------

__global__ __launch_bounds__(256) void hist_kernel(const int* __restrict__ dst,
                                                   int* __restrict__ counts) {
  int e = blockIdx.x * 256 + threadIdx.x;
  if (e < EE) atomicAdd(&counts[dst[e]], 1);
}

__global__ __launch_bounds__(1024) void scanA_kernel(const int* __restrict__ cnts,
                                                     int* __restrict__ excl,
                                                     int* __restrict__ bsum) {
  __shared__ int sb[1024];
  int b = blockIdx.x, tid = threadIdx.x;
  int idx = b * 1024 + tid;
  int c = (idx < NN) ? cnts[idx] : 0;
  int v = c;
  sb[tid] = v;
  __syncthreads();
  for (int off = 1; off < 1024; off <<= 1) {
    int t = (tid >= off) ? sb[tid - off] : 0;
    __syncthreads();
    v += t;
    sb[tid] = v;
    __syncthreads();
  }
  if (idx < NN) excl[idx] = v - c;
  if (tid == 1023) bsum[b] = v;
}

__global__ __launch_bounds__(128) void scanB_kernel(int* __restrict__ bsum) {
  __shared__ int sb[128];
  int tid = threadIdx.x;
  int c = (tid < 98) ? bsum[tid] : 0;
  int v = c;
  sb[tid] = v;
  __syncthreads();
  for (int off = 1; off < 128; off <<= 1) {
    int t = (tid >= off) ? sb[tid - off] : 0;
    __syncthreads();
    v += t;
    sb[tid] = v;
    __syncthreads();
  }
  if (tid < 98) bsum[tid] = v - c;
}

__global__ __launch_bounds__(256) void scanC_kernel(const int* __restrict__ bsum,
                                                    int* __restrict__ rs,
                                                    int* __restrict__ cur) {
  int i = blockIdx.x * 256 + threadIdx.x;
  if (i < NN) {
    int v = rs[i] + bsum[i >> 10];
    rs[i] = v;
    cur[i] = v;
  }
  if (i == 0) rs[NN] = EE;
}

__global__ __launch_bounds__(256) void fill_kernel(const int* __restrict__ src,
                                                   const int* __restrict__ dst,
                                                   int* __restrict__ cursor,
                                                   int* __restrict__ csr) {
  int e = blockIdx.x * 256 + threadIdx.x;
  if (e < EE) {
    int p = atomicAdd(&cursor[dst[e]], 1);
    csr[p] = src[e];
  }
}

// ---------------- bf16 convert of x ----------------

__global__ __launch_bounds__(256) void convb_kernel(const float* __restrict__ x,
                                                    u16* __restrict__ xb) {
  int i = blockIdx.x * 256 + threadIdx.x;
  if (i < NN * 75) xb[i] = f2b(x[i]);
}

// ---------------- aggregation + eps (bf16 gather, fp32 accumulate) ----------------

__global__ __launch_bounds__(256) void aggz_kernel(const float* __restrict__ xt, int xs,
                                                   const u16* __restrict__ xb,
                                                   const int* __restrict__ rs,
                                                   const int* __restrict__ csr,
                                                   const float* __restrict__ eps,
                                                   float* __restrict__ z) {
  int tid = threadIdx.x;
  if (tid >= 225) return;
  int local = tid / 75;
  int f = tid - local * 75;
  int n = blockIdx.x * 3 + local;
  if (n >= NN) return;
  int e0 = rs[n], e1 = rs[n + 1];
  float s0 = 0.f, s1 = 0.f, s2 = 0.f, s3 = 0.f;
  int e = e0;
  for (; e + 3 < e1; e += 4) {
    int a = csr[e], b = csr[e + 1], c = csr[e + 2], d = csr[e + 3];
    s0 += b2f(xb[a * 75 + f]);
    s1 += b2f(xb[b * 75 + f]);
    s2 += b2f(xb[c * 75 + f]);
    s3 += b2f(xb[d * 75 + f]);
  }
  for (; e < e1; ++e) s0 += b2f(xb[csr[e] * 75 + f]);
  float ep = 1.0f + eps[0];
  z[n * 75 + f] = ep * xt[n * xs + f] + ((s0 + s1) + (s2 + s3));
}

// ---------------- GEMM helpers (transposed-A, XOR-swizzled LDS) ----------------
// A^T tile: at[c*R + (r ^ ((c&15)<<2))] = A[r][c]  (R = 64 or 128, c = k index 0..74)

__device__ __forceinline__ void stagew_pad(const float* __restrict__ W, float* wsx, int tid) {
  // wsx[k*80+f] = W[k*75+f], zero pad f>=75
  for (int i = tid; i < 6000; i += 256) {
    int k = i / 80, f = i - k * 80;
    wsx[i] = (f < 75) ? W[k * 75 + f] : 0.f;
  }
}

__device__ __forceinline__ void stagew_tr(const float* __restrict__ W, int off, float* wsx,
                                          int tid) {
  // wsx[k*80+f] = W[(off+f)*75+k], zero pad
  for (int i = tid; i < 6000; i += 256) {
    int k = i / 80, f = i - k * 80;
    wsx[i] = (f < 75) ? W[(off + f) * 75 + k] : 0.f;
  }
}

__device__ __forceinline__ void kloopT4(const float* at, const float* wsx, int ty, int tx,
                                        float acc[4][5]) {
#pragma unroll 5
  for (int k = 0; k < 75; ++k) {
    int q = (k & 15) << 2;
    float4 a = *reinterpret_cast<const float4*>(&at[(k << 6) + ((ty << 2) ^ q)]);
    float av[4] = {a.x, a.y, a.z, a.w};
    float w[5];
#pragma unroll
    for (int j = 0; j < 5; ++j) w[j] = wsx[k * 80 + tx + 16 * j];
#pragma unroll
    for (int i = 0; i < 4; ++i)
#pragma unroll
      for (int j = 0; j < 5; ++j) acc[i][j] += av[i] * w[j];
  }
}

__device__ __forceinline__ void kloopT8(const float* at, const float* wsx, int ty, int tx,
                                        float acc[8][5]) {
#pragma unroll 3
  for (int k = 0; k < 75; ++k) {
    int q = (k & 15) << 2;
    int base = (k << 7) + ((ty << 3) ^ q);
    float4 a0 = *reinterpret_cast<const float4*>(&at[base]);
    float4 a1 = *reinterpret_cast<const float4*>(&at[base ^ 4]);
    float av[8] = {a0.x, a0.y, a0.z, a0.w, a1.x, a1.y, a1.z, a1.w};
    float w[5];
#pragma unroll
    for (int j = 0; j < 5; ++j) w[j] = wsx[k * 80 + tx + 16 * j];
#pragma unroll
    for (int i = 0; i < 8; ++i)
#pragma unroll
      for (int j = 0; j < 5; ++j) acc[i][j] += av[i] * w[j];
  }
}

__device__ __forceinline__ void kloopT4x10(const float* at, const float* wsx, int ty, int tx,
                                           float acc[4][10]) {
#pragma unroll 5
  for (int k = 0; k < 75; ++k) {
    int q = (k & 15) << 2;
    float4 a = *reinterpret_cast<const float4*>(&at[(k << 6) + ((ty << 2) ^ q)]);
    float av[4] = {a.x, a.y, a.z, a.w};
    float w[10];
#pragma unroll
    for (int j = 0; j < 10; ++j) w[j] = wsx[k * 160 + tx + 16 * j];
#pragma unroll
    for (int i = 0; i < 4; ++i)
#pragma unroll
      for (int j = 0; j < 10; ++j) acc[i][j] += av[i] * w[j];
  }
}

// ---------------- GIN MLP (in-place z -> m), 128-row tiles ----------------

__global__ __launch_bounds__(256) void mlp_kernel(float* __restrict__ z,
                                                  const float* __restrict__ w1,
                                                  const float* __restrict__ b1,
                                                  const float* __restrict__ w2,
                                                  const float* __restrict__ b2) {
  __shared__ float at[75 * 128];
  __shared__ float wsx[6000];
  __shared__ float b1s[80], b2s[80];
  int tid = threadIdx.x;
  int row0 = blockIdx.x * 128;
  if (tid < 80) {
    b1s[tid] = (tid < 75) ? b1[tid] : 0.f;
    b2s[tid] = (tid < 75) ? b2[tid] : 0.f;
  }
  stagew_pad(w1, wsx, tid);
  for (int i = tid; i < 128 * 75; i += 256) {
    int r = i / 75, c = i - r * 75;
    int gr = row0 + r;
    at[c * 128 + (r ^ ((c & 15) << 2))] = (gr < NN) ? z[gr * 75 + c] : 0.f;
  }
  __syncthreads();
  int ty = tid >> 4, tx = tid & 15;
  float acc[8][5];
#pragma unroll
  for (int i = 0; i < 8; ++i)
#pragma unroll
    for (int j = 0; j < 5; ++j) acc[i][j] = b1s[tx + 16 * j];
  kloopT8(at, wsx, ty, tx, acc);
  __syncthreads();
#pragma unroll
  for (int i = 0; i < 8; ++i)
#pragma unroll
    for (int j = 0; j < 5; ++j) {
      int f = tx + 16 * j;
      if (f < 75) at[f * 128 + (((ty << 3) + i) ^ ((f & 15) << 2))] = fmaxf(acc[i][j], 0.f);
    }
  stagew_pad(w2, wsx, tid);
  __syncthreads();
  float acc2[8][5];
#pragma unroll
  for (int i = 0; i < 8; ++i)
#pragma unroll
    for (int j = 0; j < 5; ++j) acc2[i][j] = b2s[tx + 16 * j];
  kloopT8(at, wsx, ty, tx, acc2);
#pragma unroll
  for (int i = 0; i < 8; ++i)
#pragma unroll
    for (int j = 0; j < 5; ++j) {
      int f = tx + 16 * j;
      int gr = row0 + (ty << 3) + i;
      if (f < 75 && gr < NN) z[gr * 75 + f] = fmaxf(acc2[i][j], 0.f);
    }
}

// ---------------- GRU step, 64-row tiles ----------------

__global__ __launch_bounds__(256) void gru_kernel(const float* __restrict__ m,
                                                  const float* __restrict__ h, int hs,
                                                  const float* __restrict__ w_ih,
                                                  const float* __restrict__ w_hh,
                                                  const float* __restrict__ b_ih,
                                                  const float* __restrict__ b_hh,
                                                  float* __restrict__ hout,
                                                  u16* __restrict__ xbout,
                                                  float* __restrict__ hout2) {
  __shared__ float mt[75 * 64];
  __shared__ float ht[75 * 64];
  __shared__ float wsx[6000];
  __shared__ float bih[240], bhh[240];
  int tid = threadIdx.x;
  int row0 = blockIdx.x * 64;
  if (tid < 240) {
    bih[tid] = (tid < 225) ? b_ih[tid] : 0.f;
    bhh[tid] = (tid < 225) ? b_hh[tid] : 0.f;
  }
  for (int i = tid; i < 64 * 75; i += 256) {
    int r = i / 75, c = i - r * 75;
    int gr = row0 + r;
    int sw = c * 64 + (r ^ ((c & 15) << 2));
    mt[sw] = (gr < NN) ? m[gr * 75 + c] : 0.f;
    ht[sw] = (gr < NN) ? h[gr * hs + c] : 0.f;
  }
  stagew_tr(w_ih, 0, wsx, tid);
  __syncthreads();
  int ty = tid >> 4, tx = tid & 15;
  float gr_[4][5], gz_[4][5], an_[4][5], hn_[4][5];
#pragma unroll
  for (int i = 0; i < 4; ++i)
#pragma unroll
    for (int j = 0; j < 5; ++j) {
      int f = tx + 16 * j;
      gr_[i][j] = bih[f] + bhh[f];
      gz_[i][j] = bih[75 + f] + bhh[75 + f];
      an_[i][j] = bih[150 + f];
      hn_[i][j] = bhh[150 + f];
    }
  kloopT4(mt, wsx, ty, tx, gr_);
  __syncthreads();
  stagew_tr(w_hh, 0, wsx, tid);
  __syncthreads();
  kloopT4(ht, wsx, ty, tx, gr_);
#pragma unroll
  for (int i = 0; i < 4; ++i)
#pragma unroll
    for (int j = 0; j < 5; ++j) gr_[i][j] = 1.f / (1.f + __expf(-gr_[i][j]));
  __syncthreads();
  stagew_tr(w_ih, 75, wsx, tid);
  __syncthreads();
  kloopT4(mt, wsx, ty, tx, gz_);
  __syncthreads();
  stagew_tr(w_hh, 75, wsx, tid);
  __syncthreads();
  kloopT4(ht, wsx, ty, tx, gz_);
#pragma unroll
  for (int i = 0; i < 4; ++i)
#pragma unroll
    for (int j = 0; j < 5; ++j) gz_[i][j] = 1.f / (1.f + __expf(-gz_[i][j]));
  __syncthreads();
  stagew_tr(w_ih, 150, wsx, tid);
  __syncthreads();
  kloopT4(mt, wsx, ty, tx, an_);
  __syncthreads();
  stagew_tr(w_hh, 150, wsx, tid);
  __syncthreads();
  kloopT4(ht, wsx, ty, tx, hn_);
#pragma unroll
  for (int i = 0; i < 4; ++i)
#pragma unroll
    for (int j = 0; j < 5; ++j) {
      int f = tx + 16 * j;
      int r = (ty << 2) + i;
      int gn = row0 + r;
      if (f < 75 && gn < NN) {
        float nv = tanhf(an_[i][j] + gr_[i][j] * hn_[i][j]);
        float hv = ht[f * 64 + (r ^ ((f & 15) << 2))];
        float o = (1.f - gz_[i][j]) * nv + gz_[i][j] * hv;
        hout[gn * 225 + f] = o;
        xbout[gn * 75 + f] = f2b(o);
        if (hout2) hout2[gn * 75 + f] = o;
      }
    }
}

// ---------------- readout ----------------

__global__ __launch_bounds__(256) void read1_kernel(const float* __restrict__ cat,
                                                    const float* __restrict__ wc1,
                                                    const float* __restrict__ bc1,
                                                    u16* __restrict__ r1) {
  __shared__ float at[75 * 64];
  __shared__ float wsx[12000];
  __shared__ float bias[160];
  int tid = threadIdx.x;
  int row0 = blockIdx.x * 64;
  if (tid < 160) bias[tid] = (tid < 150) ? bc1[tid] : 0.f;
  __syncthreads();
  int ty = tid >> 4, tx = tid & 15;
  float acc[4][10];
#pragma unroll
  for (int i = 0; i < 4; ++i)
#pragma unroll
    for (int j = 0; j < 10; ++j) acc[i][j] = bias[tx + 16 * j];
  for (int kc = 0; kc < 3; ++kc) {
    __syncthreads();
    for (int i = tid; i < 12000; i += 256) {
      int k = i / 160, f = i - k * 160;
      wsx[i] = (f < 150) ? wc1[kc * 11250 + k * 150 + f] : 0.f;
    }
    for (int i = tid; i < 64 * 75; i += 256) {
      int r = i / 75, c = i - r * 75;
      int gr = row0 + r;
      at[c * 64 + (r ^ ((c & 15) << 2))] = (gr < NN) ? cat[gr * 225 + kc * 75 + c] : 0.f;
    }
    __syncthreads();
    kloopT4x10(at, wsx, ty, tx, acc);
  }
#pragma unroll
  for (int i = 0; i < 4; ++i)
#pragma unroll
    for (int j = 0; j < 10; ++j) {
      int f = tx + 16 * j;
      int gr = row0 + (ty << 2) + i;
      if (f < 150 && gr < NN) r1[gr * 150 + f] = f2b(fmaxf(acc[i][j], 0.f));
    }
}

__global__ __launch_bounds__(256) void read2_kernel(const u16* __restrict__ r1,
                                                    const float* __restrict__ wc2,
                                                    const float* __restrict__ bc2,
                                                    float* __restrict__ out) {
  __shared__ float at[75 * 64];
  __shared__ float wsx[6000];
  __shared__ float bias[80];
  int tid = threadIdx.x;
  int row0 = blockIdx.x * 64;
  if (tid < 80) bias[tid] = (tid < 75) ? bc2[tid] : 0.f;
  __syncthreads();
  int ty = tid >> 4, tx = tid & 15;
  float acc[4][5];
#pragma unroll
  for (int i = 0; i < 4; ++i)
#pragma unroll
    for (int j = 0; j < 5; ++j) acc[i][j] = bias[tx + 16 * j];
  for (int kc = 0; kc < 2; ++kc) {
    __syncthreads();
    for (int i = tid; i < 6000; i += 256) {
      int k = i / 80, f = i - k * 80;
      wsx[i] = (f < 75) ? wc2[kc * 5625 + k * 75 + f] : 0.f;
    }
    for (int i = tid; i < 64 * 75; i += 256) {
      int r = i / 75, c = i - r * 75;
      int gr = row0 + r;
      at[c * 64 + (r ^ ((c & 15) << 2))] = (gr < NN) ? b2f(r1[gr * 150 + kc * 75 + c]) : 0.f;
    }
    __syncthreads();
    kloopT4(at, wsx, ty, tx, acc);
  }
#pragma unroll
  for (int i = 0; i < 4; ++i)
#pragma unroll
    for (int j = 0; j < 5; ++j) {
      int f = tx + 16 * j;
      int gr = row0 + (ty << 2) + i;
      if (f < 75 && gr < NN) out[gr * 75 + f] = acc[i][j];
    }
}

// ---------------- launch ----------------

extern "C" void kernel_launch(void* const* d_in, const int* in_sizes, int n_in,
                              void* d_out, int out_size, void* d_ws, size_t ws_size,
                              hipStream_t stream) {
  const float* x    = (const float*)d_in[0];
  const int*   ei   = (const int*)d_in[1];
  const float* eps  = (const float*)d_in[2];
  const float* w1   = (const float*)d_in[3];
  const float* b1   = (const float*)d_in[4];
  const float* w2   = (const float*)d_in[5];
  const float* b2   = (const float*)d_in[6];
  const float* w_ih = (const float*)d_in[7];
  const float* w_hh = (const float*)d_in[8];
  const float* b_ih = (const float*)d_in[9];
  const float* b_hh = (const float*)d_in[10];
  const float* wc1  = (const float*)d_in[11];
  const float* bc1  = (const float*)d_in[12];
  const float* wc2  = (const float*)d_in[13];
  const float* bc2  = (const float*)d_in[14];

  const int* srcv = ei;
  const int* dstv = ei + EE;

  float* out_x = (float*)d_out;            // N*75 final node states
  float* out_r = out_x + NN * 75;          // N*75 readout

  float* wsf  = (float*)d_ws;
  float* zb   = wsf;                       // 7.5M floats: z / m (in-place); r1(bf16) later
  float* catb = wsf + 7500000;             // 22.5M floats
  u16*   xb   = (u16*)(wsf + 30000000);    // 7.5M u16
  int*   csr  = (int*)(wsf + 33750000);    // E ints
  int*   rs   = csr + EE;                  // N+1
  int*   cur  = rs + (NN + 1);             // N
  int*   cnt  = (int*)zb;                  // aliased: used only pre-iteration
  int*   bsum = cnt + NN;                  // 128, aliased in zb
  u16*   r1b  = (u16*)zb;                  // aliased: used only post-iteration (15M u16)

  hipMemsetAsync(cnt, 0, NN * sizeof(int), stream);
  hist_kernel<<<(EE + 255) / 256, 256, 0, stream>>>(dstv, cnt);
  scanA_kernel<<<(NN + 1023) / 1024, 1024, 0, stream>>>(cnt, rs, bsum);
  scanB_kernel<<<1, 128, 0, stream>>>(bsum);
  scanC_kernel<<<(NN + 255) / 256, 256, 0, stream>>>(bsum, rs, cur);
  fill_kernel<<<(EE + 255) / 256, 256, 0, stream>>>(srcv, dstv, cur, csr);
  convb_kernel<<<(NN * 75 + 255) / 256, 256, 0, stream>>>(x, xb);

  const float* xt = x;
  int xs = 75;
  for (int it = 0; it < 3; ++it) {
    aggz_kernel<<<(NN + 2) / 3, 256, 0, stream>>>(xt, xs, xb, rs, csr, eps, zb);
    mlp_kernel<<<(NN + 127) / 128, 256, 0, stream>>>(zb, w1, b1, w2, b2);
    gru_kernel<<<(NN + 63) / 64, 256, 0, stream>>>(zb, xt, xs, w_ih, w_hh, b_ih, b_hh,
                                                   catb + it * 75, xb,
                                                   (it == 2) ? out_x : nullptr);
    xt = catb + it * 75;
    xs = 225;
  }
  read1_kernel<<<(NN + 63) / 64, 256, 0, stream>>>(catb, wc1, bc1, r1b);
  read2_kernel<<<(NN + 63) / 64, 256, 0, stream>>>(r1b, wc2, bc2, out_r);
}

// Round 3
// 1061.755 us; speedup vs baseline: 2.7473x; 2.2604x over previous
//
#include <hip/hip_runtime.h>

#define NN 100000
#define EE 3200000
#define N2 100032   // NN rounded up to 64

typedef _Float16 f16;
typedef _Float16 f16x2 __attribute__((ext_vector_type(2)));
typedef _Float16 f16x8 __attribute__((ext_vector_type(8)));
typedef float f32x4 __attribute__((ext_vector_type(4)));

#define MFMA(a, b, c) __builtin_amdgcn_mfma_f32_16x16x32_f16((a), (b), (c), 0, 0, 0)

// ---------------- CSR build ----------------

__global__ __launch_bounds__(256) void hist_kernel(const int* __restrict__ dst,
                                                   int* __restrict__ counts) {
  int e = blockIdx.x * 256 + threadIdx.x;
  if (e < EE) atomicAdd(&counts[dst[e]], 1);
}

__global__ __launch_bounds__(1024) void scanA_kernel(const int* __restrict__ cnts,
                                                     int* __restrict__ excl,
                                                     int* __restrict__ bsum) {
  __shared__ int sb[1024];
  int b = blockIdx.x, tid = threadIdx.x;
  int idx = b * 1024 + tid;
  int c = (idx < NN) ? cnts[idx] : 0;
  int v = c;
  sb[tid] = v;
  __syncthreads();
  for (int off = 1; off < 1024; off <<= 1) {
    int t = (tid >= off) ? sb[tid - off] : 0;
    __syncthreads();
    v += t;
    sb[tid] = v;
    __syncthreads();
  }
  if (idx < NN) excl[idx] = v - c;
  if (tid == 1023) bsum[b] = v;
}

__global__ __launch_bounds__(128) void scanB_kernel(int* __restrict__ bsum) {
  __shared__ int sb[128];
  int tid = threadIdx.x;
  int c = (tid < 98) ? bsum[tid] : 0;
  int v = c;
  sb[tid] = v;
  __syncthreads();
  for (int off = 1; off < 128; off <<= 1) {
    int t = (tid >= off) ? sb[tid - off] : 0;
    __syncthreads();
    v += t;
    sb[tid] = v;
    __syncthreads();
  }
  if (tid < 98) bsum[tid] = v - c;
}

__global__ __launch_bounds__(256) void scanC_kernel(const int* __restrict__ bsum,
                                                    int* __restrict__ rs,
                                                    int* __restrict__ cur) {
  int i = blockIdx.x * 256 + threadIdx.x;
  if (i < NN) {
    int v = rs[i] + bsum[i >> 10];
    rs[i] = v;
    cur[i] = v;
  }
  if (i == 0) rs[NN] = EE;
}

__global__ __launch_bounds__(256) void fill_kernel(const int* __restrict__ src,
                                                   const int* __restrict__ dst,
                                                   int* __restrict__ cursor,
                                                   int* __restrict__ csr) {
  int e = blockIdx.x * 256 + threadIdx.x;
  if (e < EE) {
    int p = atomicAdd(&cursor[dst[e]], 1);
    csr[p] = src[e];
  }
}

// ---------------- weight pack into B-fragment order ----------------
// dst[((nb*KG + g)*16 + nn)*8 + e] = W[k= g*8+e][n= nb*16+nn]  (zero-padded)
// trans: logical W[k][n] = Wsrc[n*K + k]

__global__ __launch_bounds__(256) void pack_kernel(const float* __restrict__ W, int K, int Nc,
                                                   int KG, int NB, int trans,
                                                   f16* __restrict__ dst) {
  int i = blockIdx.x * 256 + threadIdx.x;
  if (i >= NB * KG * 128) return;
  int e = i & 7, nn = (i >> 3) & 15;
  int g = (i >> 7) % KG, nb = (i >> 7) / KG;
  int k = g * 8 + e, n = nb * 16 + nn;
  float v = 0.f;
  if (k < K && n < Nc) v = trans ? W[n * K + k] : W[k * Nc + n];
  dst[i] = (f16)v;
}

// ---------------- x -> padded f16 ----------------

__global__ __launch_bounds__(256) void convx_kernel(const float* __restrict__ x,
                                                    f16* __restrict__ xp) {
  int i = blockIdx.x * 256 + threadIdx.x;
  if (i >= N2 * 96) return;
  int r = i / 96, c = i - r * 96;
  xp[i] = (f16)((r < NN && c < 75) ? x[r * 75 + c] : 0.f);
}

// ---------------- aggregation: z = (1+eps)*h + sum_in h[src]  (f16 in/out, padded 96) ----------------

__global__ __launch_bounds__(256) void aggz_kernel(const f16* __restrict__ xc,
                                                   const int* __restrict__ rs,
                                                   const int* __restrict__ csr,
                                                   const float* __restrict__ eps,
                                                   f16* __restrict__ zm) {
  int tid = threadIdx.x;
  int n0 = blockIdx.x * 6;
  const f16x2* x2 = (const f16x2*)xc;
  f16x2* z2 = (f16x2*)zm;
  if (tid < 228) {
    int local = tid / 38, j = tid - local * 38;   // j covers features 2j, 2j+1 (j<38 -> cols 0..75)
    int n = n0 + local;
    if (n >= NN) return;
    int e0 = rs[n], e1 = rs[n + 1];
    float s0 = 0, s1 = 0, s2 = 0, s3 = 0, t0 = 0, t1 = 0, t2 = 0, t3 = 0;
    int e = e0;
    for (; e + 3 < e1; e += 4) {
      int a = csr[e], b = csr[e + 1], c = csr[e + 2], d = csr[e + 3];
      f16x2 va = x2[a * 48 + j], vb = x2[b * 48 + j], vc = x2[c * 48 + j], vd = x2[d * 48 + j];
      s0 += (float)va.x; t0 += (float)va.y;
      s1 += (float)vb.x; t1 += (float)vb.y;
      s2 += (float)vc.x; t2 += (float)vc.y;
      s3 += (float)vd.x; t3 += (float)vd.y;
    }
    for (; e < e1; ++e) { f16x2 v = x2[csr[e] * 48 + j]; s0 += (float)v.x; t0 += (float)v.y; }
    float ep = 1.f + eps[0];
    f16x2 self = x2[n * 48 + j];
    f16x2 o;
    o.x = (f16)(ep * (float)self.x + ((s0 + s1) + (s2 + s3)));
    o.y = (f16)(ep * (float)self.y + ((t0 + t1) + (t2 + t3)));
    z2[n * 48 + j] = o;
  } else {
    int t = tid - 228;
    for (int i = t; i < 60; i += 28) {        // zero pad cols 76..95 (u32 j = 38..47)
      int local = i / 10, j = 38 + (i - (i / 10) * 10);
      int n = n0 + local;
      if (n < NN) z2[n * 48 + j] = (f16x2){(f16)0.f, (f16)0.f};
    }
  }
}

// ---------------- fused GIN MLP (in-place zm: z -> m), MFMA ----------------

__global__ __launch_bounds__(256) void mlp_kernel(f16* __restrict__ zm,
                                                  const f16* __restrict__ w1p,
                                                  const f16* __restrict__ w2p,
                                                  const float* __restrict__ b1,
                                                  const float* __restrict__ b2) {
  __shared__ f16 m1lds[4][16 * 104];
  int tid = threadIdx.x;
  int w = tid >> 6, l = tid & 63, lm = l & 15, lg = l >> 4;
  int row = blockIdx.x * 64 + w * 16 + lm;
  const f16* ar = zm + row * 96;
  f16x8 a0 = *(const f16x8*)(ar + lg * 8);
  f16x8 a1 = *(const f16x8*)(ar + 32 + lg * 8);
  f16x8 a2 = *(const f16x8*)(ar + 64 + lg * 8);
  f32x4 acc[5];
#pragma unroll
  for (int nb = 0; nb < 5; ++nb) {
    int n = nb * 16 + lm;
    float bv = (n < 75) ? b1[n] : 0.f;
    acc[nb] = (f32x4){bv, bv, bv, bv};
    const f16* bp = w1p + ((nb * 12 + lg) * 16 + lm) * 8;
    acc[nb] = MFMA(a0, *(const f16x8*)bp, acc[nb]);
    acc[nb] = MFMA(a1, *(const f16x8*)(bp + 512), acc[nb]);
    acc[nb] = MFMA(a2, *(const f16x8*)(bp + 1024), acc[nb]);
  }
  f16* Ld = m1lds[w];
#pragma unroll
  for (int nb = 0; nb < 5; ++nb)
#pragma unroll
    for (int r = 0; r < 4; ++r)
      Ld[(lg * 4 + r) * 104 + nb * 16 + lm] = (f16)fmaxf(acc[nb][r], 0.f);
#pragma unroll
  for (int c = 0; c < 4; ++c) Ld[lm * 104 + 80 + lg * 4 + c] = (f16)0.f;  // zero cols 80..95
  __syncthreads();
  const f16* Lr = m1lds[w] + lm * 104;
  f16x8 c0 = *(const f16x8*)(Lr + lg * 8);
  f16x8 c1 = *(const f16x8*)(Lr + 32 + lg * 8);
  f16x8 c2 = *(const f16x8*)(Lr + 64 + lg * 8);
  f32x4 acc2[5];
#pragma unroll
  for (int nb = 0; nb < 5; ++nb) {
    int n = nb * 16 + lm;
    float bv = (n < 75) ? b2[n] : 0.f;
    acc2[nb] = (f32x4){bv, bv, bv, bv};
    const f16* bp = w2p + ((nb * 12 + lg) * 16 + lm) * 8;
    acc2[nb] = MFMA(c0, *(const f16x8*)bp, acc2[nb]);
    acc2[nb] = MFMA(c1, *(const f16x8*)(bp + 512), acc2[nb]);
    acc2[nb] = MFMA(c2, *(const f16x8*)(bp + 1024), acc2[nb]);
  }
  f16* orow = zm + (blockIdx.x * 64 + w * 16) * 96;
#pragma unroll
  for (int nb = 0; nb < 5; ++nb)
#pragma unroll
    for (int r = 0; r < 4; ++r)
      orow[(lg * 4 + r) * 96 + nb * 16 + lm] = (f16)fmaxf(acc2[nb][r], 0.f);
}

// ---------------- GRU step, MFMA ----------------

__global__ __launch_bounds__(256) void gru_kernel(const f16* __restrict__ zm,
                                                  const f16* __restrict__ hcur,
                                                  const f16* __restrict__ wihp,
                                                  const f16* __restrict__ whhp,
                                                  const float* __restrict__ bih,
                                                  const float* __restrict__ bhh,
                                                  f16* __restrict__ xnext,
                                                  f16* __restrict__ catb, int itoff,
                                                  float* __restrict__ outx) {
  int tid = threadIdx.x;
  int w = tid >> 6, l = tid & 63, lm = l & 15, lg = l >> 4;
  int row0 = blockIdx.x * 64 + w * 16;
  const f16* mr = zm + (row0 + lm) * 96;
  const f16* hr = hcur + (row0 + lm) * 96;
  f16x8 am[3], ah[3];
#pragma unroll
  for (int s = 0; s < 3; ++s) {
    am[s] = *(const f16x8*)(mr + s * 32 + lg * 8);
    ah[s] = *(const f16x8*)(hr + s * 32 + lg * 8);
  }
  f32x4 rg[5], zg[5], ni[5], nh[5];
#pragma unroll
  for (int nb = 0; nb < 5; ++nb) {
    int n = nb * 16 + lm;
    float br = 0, bz = 0, bi = 0, bh = 0;
    if (n < 75) {
      br = bih[n] + bhh[n];
      bz = bih[75 + n] + bhh[75 + n];
      bi = bih[150 + n];
      bh = bhh[150 + n];
    }
    rg[nb] = (f32x4){br, br, br, br};
    zg[nb] = (f32x4){bz, bz, bz, bz};
    ni[nb] = (f32x4){bi, bi, bi, bi};
    nh[nb] = (f32x4){bh, bh, bh, bh};
#pragma unroll
    for (int s = 0; s < 3; ++s) {
      int fo = ((nb * 12 + s * 4 + lg) * 16 + lm) * 8;
      rg[nb] = MFMA(am[s], *(const f16x8*)(wihp + fo), rg[nb]);
      rg[nb] = MFMA(ah[s], *(const f16x8*)(whhp + fo), rg[nb]);
      zg[nb] = MFMA(am[s], *(const f16x8*)(wihp + 7680 + fo), zg[nb]);
      zg[nb] = MFMA(ah[s], *(const f16x8*)(whhp + 7680 + fo), zg[nb]);
      ni[nb] = MFMA(am[s], *(const f16x8*)(wihp + 15360 + fo), ni[nb]);
      nh[nb] = MFMA(ah[s], *(const f16x8*)(whhp + 15360 + fo), nh[nb]);
    }
  }
#pragma unroll
  for (int nb = 0; nb < 5; ++nb)
#pragma unroll
    for (int r = 0; r < 4; ++r) {
      int n = nb * 16 + lm;
      int grow = row0 + lg * 4 + r;
      float hval = (float)hcur[grow * 96 + n];
      float rv = 1.f / (1.f + __expf(-rg[nb][r]));
      float zv = 1.f / (1.f + __expf(-zg[nb][r]));
      float nv = tanhf(ni[nb][r] + rv * nh[nb][r]);
      float hp = (1.f - zv) * nv + zv * hval;
      if (xnext) xnext[grow * 96 + n] = (f16)hp;
      if (n < 75) {
        catb[grow * 256 + itoff + n] = (f16)hp;
        if (outx && grow < NN) outx[grow * 75 + n] = hp;
      }
    }
}

// ---------------- readout ----------------

__global__ __launch_bounds__(256) void read1_kernel(const f16* __restrict__ catb,
                                                    const f16* __restrict__ wc1p,
                                                    const float* __restrict__ bc1,
                                                    f16* __restrict__ r1b) {
  int tid = threadIdx.x;
  int w = tid >> 6, l = tid & 63, lm = l & 15, lg = l >> 4;
  int row0 = blockIdx.x * 64 + w * 16;
  const f16* ar = catb + (row0 + lm) * 256;
  f16x8 a[8];
#pragma unroll
  for (int s = 0; s < 8; ++s) a[s] = *(const f16x8*)(ar + s * 32 + lg * 8);
  f32x4 acc[10];
#pragma unroll
  for (int nb = 0; nb < 10; ++nb) {
    int n = nb * 16 + lm;
    float bv = (n < 150) ? bc1[n] : 0.f;
    acc[nb] = (f32x4){bv, bv, bv, bv};
#pragma unroll
    for (int s = 0; s < 8; ++s)
      acc[nb] = MFMA(a[s], *(const f16x8*)(wc1p + ((nb * 32 + s * 4 + lg) * 16 + lm) * 8),
                     acc[nb]);
  }
  f16* orow = r1b + row0 * 160;
#pragma unroll
  for (int nb = 0; nb < 10; ++nb)
#pragma unroll
    for (int r = 0; r < 4; ++r)
      orow[(lg * 4 + r) * 160 + nb * 16 + lm] = (f16)fmaxf(acc[nb][r], 0.f);
}

__global__ __launch_bounds__(256) void read2_kernel(const f16* __restrict__ r1b,
                                                    const f16* __restrict__ wc2p,
                                                    const float* __restrict__ bc2,
                                                    float* __restrict__ out) {
  int tid = threadIdx.x;
  int w = tid >> 6, l = tid & 63, lm = l & 15, lg = l >> 4;
  int row0 = blockIdx.x * 64 + w * 16;
  const f16* ar = r1b + (row0 + lm) * 160;
  f16x8 a[5];
#pragma unroll
  for (int s = 0; s < 5; ++s) a[s] = *(const f16x8*)(ar + s * 32 + lg * 8);
  f32x4 acc[5];
#pragma unroll
  for (int nb = 0; nb < 5; ++nb) {
    int n = nb * 16 + lm;
    float bv = (n < 75) ? bc2[n] : 0.f;
    acc[nb] = (f32x4){bv, bv, bv, bv};
#pragma unroll
    for (int s = 0; s < 5; ++s)
      acc[nb] = MFMA(a[s], *(const f16x8*)(wc2p + ((nb * 20 + s * 4 + lg) * 16 + lm) * 8),
                     acc[nb]);
  }
#pragma unroll
  for (int nb = 0; nb < 5; ++nb)
#pragma unroll
    for (int r = 0; r < 4; ++r) {
      int n = nb * 16 + lm;
      int grow = row0 + lg * 4 + r;
      if (n < 75 && grow < NN) out[grow * 75 + n] = acc[nb][r];
    }
}

// ---------------- launch ----------------

extern "C" void kernel_launch(void* const* d_in, const int* in_sizes, int n_in,
                              void* d_out, int out_size, void* d_ws, size_t ws_size,
                              hipStream_t stream) {
  const float* x    = (const float*)d_in[0];
  const int*   ei   = (const int*)d_in[1];
  const float* eps  = (const float*)d_in[2];
  const float* w1   = (const float*)d_in[3];
  const float* b1   = (const float*)d_in[4];
  const float* w2   = (const float*)d_in[5];
  const float* b2   = (const float*)d_in[6];
  const float* w_ih = (const float*)d_in[7];
  const float* w_hh = (const float*)d_in[8];
  const float* b_ih = (const float*)d_in[9];
  const float* b_hh = (const float*)d_in[10];
  const float* wc1  = (const float*)d_in[11];
  const float* bc1  = (const float*)d_in[12];
  const float* wc2  = (const float*)d_in[13];
  const float* bc2  = (const float*)d_in[14];

  const int* srcv = ei;
  const int* dstv = ei + EE;

  float* out_x = (float*)d_out;              // N*75 final node states (fp32)
  float* out_r = out_x + NN * 75;            // N*75 readout (fp32)

  f16* zm   = (f16*)d_ws;                    // N2*96
  f16* xpB  = zm + (size_t)N2 * 96;          // N2*96
  f16* xpA  = xpB + (size_t)N2 * 96;         // N2*96
  f16* catb = xpA + (size_t)N2 * 96;         // N2*256
  f16* wp   = catb + (size_t)N2 * 256;       // packed weights, 115200 f16
  f16* w1p  = wp;
  f16* w2p  = wp + 7680;
  f16* wihp = wp + 15360;                    // 3 gates x 7680
  f16* whhp = wp + 38400;
  f16* wc1p = wp + 61440;                    // 40960
  f16* wc2p = wp + 102400;                   // 12800
  int* csr  = (int*)(wp + 115200);           // EE
  int* rsv  = csr + EE;                      // NN+1
  int* cur  = rsv + NN + 1;
  int* cnt  = cur + NN;
  int* bsum = cnt + NN;                      // 128
  f16* r1b  = zm;                            // N2*160, aliases zm+xpB (both dead by then)

  hipMemsetAsync(cnt, 0, NN * sizeof(int), stream);
  hist_kernel<<<(EE + 255) / 256, 256, 0, stream>>>(dstv, cnt);
  scanA_kernel<<<(NN + 1023) / 1024, 1024, 0, stream>>>(cnt, rsv, bsum);
  scanB_kernel<<<1, 128, 0, stream>>>(bsum);
  scanC_kernel<<<(NN + 255) / 256, 256, 0, stream>>>(bsum, rsv, cur);
  fill_kernel<<<(EE + 255) / 256, 256, 0, stream>>>(srcv, dstv, cur, csr);
  convx_kernel<<<(N2 * 96 + 255) / 256, 256, 0, stream>>>(x, xpA);

  // weight packs
  pack_kernel<<<30, 256, 0, stream>>>(w1, 75, 75, 12, 5, 0, w1p);
  pack_kernel<<<30, 256, 0, stream>>>(w2, 75, 75, 12, 5, 0, w2p);
  for (int g = 0; g < 3; ++g) {
    pack_kernel<<<30, 256, 0, stream>>>(w_ih + g * 5625, 75, 75, 12, 5, 1, wihp + g * 7680);
    pack_kernel<<<30, 256, 0, stream>>>(w_hh + g * 5625, 75, 75, 12, 5, 1, whhp + g * 7680);
  }
  pack_kernel<<<160, 256, 0, stream>>>(wc1, 225, 150, 32, 10, 0, wc1p);
  pack_kernel<<<50, 256, 0, stream>>>(wc2, 150, 75, 20, 5, 0, wc2p);

  int gb = N2 / 64;  // 1563
  for (int it = 0; it < 3; ++it) {
    const f16* h = (it == 1) ? xpB : xpA;
    f16* hn = (it == 0) ? xpB : (it == 1) ? xpA : nullptr;
    aggz_kernel<<<(NN + 5) / 6, 256, 0, stream>>>(h, rsv, csr, eps, zm);
    mlp_kernel<<<gb, 256, 0, stream>>>(zm, w1p, w2p, b1, b2);
    gru_kernel<<<gb, 256, 0, stream>>>(zm, h, wihp, whhp, b_ih, b_hh, hn, catb, it * 75,
                                       (it == 2) ? out_x : nullptr);
  }
  read1_kernel<<<gb, 256, 0, stream>>>(catb, wc1p, bc1, r1b);
  read2_kernel<<<gb, 256, 0, stream>>>(r1b, wc2p, bc2, out_r);
}